// Round 1
// baseline (1711.358 us; speedup 1.0000x reference)
//
#include <hip/hip_runtime.h>
#include <cstddef>

#define BN 4096
#define DD 128
#define NSTEPS 100
#define TILE 64
#define KSUB 64
#define LSTR 68   // KSUB + 4 pad: row stride 68 floats -> bank shift 4/row

// ---------------- normalize: one wave per row ----------------
__global__ __launch_bounds__(256) void hl_normalize(const float* __restrict__ emb,
                                                    float* __restrict__ out) {
    int w = threadIdx.x >> 6;
    int lane = threadIdx.x & 63;
    int row = (blockIdx.x << 2) + w;
    if (row >= BN) return;
    const float* r = emb + (size_t)row * DD;
    float x0 = r[lane];
    float x1 = r[lane + 64];
    float ss = x0 * x0 + x1 * x1;
    #pragma unroll
    for (int off = 32; off > 0; off >>= 1) ss += __shfl_xor(ss, off);
    float inv = 1.0f / sqrtf(ss);
    float* o = out + (size_t)row * DD;
    o[lane] = x0 * inv;
    o[lane + 64] = x1 * inv;
}

// ---------------- pair kernel: 64x64 tile pairs ----------------
__global__ __launch_bounds__(256) void hl_pair(const float* __restrict__ nemb,
                                               const int* __restrict__ cls,
                                               float* __restrict__ gPos,
                                               float* __restrict__ gNeg) {
    const int ti = blockIdx.y, tj = blockIdx.x;
    if (ti > tj) return;

    __shared__ float As[TILE][LSTR];
    __shared__ float Bs[TILE][LSTR];
    __shared__ int clsA[TILE], clsB[TILE];
    __shared__ float hPos[NSTEPS], hNeg[NSTEPS];

    const int tid = threadIdx.x;
    if (tid < NSTEPS) { hPos[tid] = 0.0f; hNeg[tid] = 0.0f; }
    if (tid >= 128 && tid < 128 + TILE) clsA[tid - 128] = cls[ti * TILE + (tid - 128)];
    if (tid >= 192)                     clsB[tid - 192] = cls[tj * TILE + (tid - 192)];

    const int tx = tid & 15;
    const int ty = tid >> 4;

    float acc[4][4] = {{0.f, 0.f, 0.f, 0.f}};

    #pragma unroll
    for (int kt = 0; kt < DD / KSUB; ++kt) {
        __syncthreads();  // also covers hist zero / cls load before first use
        // stage: 64 rows x 16 float4 per matrix, 256 threads -> 4 iters
        #pragma unroll
        for (int it = 0; it < 4; ++it) {
            int idx = it * 256 + tid;
            int row = idx >> 4;      // 0..63
            int kg = idx & 15;       // 0..15
            const float4 va = *(const float4*)(nemb + (size_t)(ti * TILE + row) * DD + kt * KSUB + kg * 4);
            const float4 vb = *(const float4*)(nemb + (size_t)(tj * TILE + row) * DD + kt * KSUB + kg * 4);
            *(float4*)(&As[row][kg * 4]) = va;
            *(float4*)(&Bs[row][kg * 4]) = vb;
        }
        __syncthreads();

        #pragma unroll
        for (int k = 0; k < KSUB; k += 4) {
            float4 av[4], bv[4];
            #pragma unroll
            for (int a = 0; a < 4; ++a) av[a] = *(const float4*)(&As[ty + 16 * a][k]);
            #pragma unroll
            for (int b = 0; b < 4; ++b) bv[b] = *(const float4*)(&Bs[tx + 16 * b][k]);
            #pragma unroll
            for (int a = 0; a < 4; ++a) {
                #pragma unroll
                for (int b = 0; b < 4; ++b) {
                    acc[a][b] += av[a].x * bv[b].x + av[a].y * bv[b].y
                               + av[a].z * bv[b].z + av[a].w * bv[b].w;
                }
            }
        }
    }

    // histogram accumulation into LDS
    constexpr float STEPF = 2.0f / 99.0f;
    constexpr float INVSTEP = 49.5f;          // exact
    constexpr float CLIPV = 1.0f - 1e-6f;

    #pragma unroll
    for (int a = 0; a < 4; ++a) {
        int li = ty + 16 * a;
        int gi = ti * TILE + li;
        int ca = clsA[li];
        #pragma unroll
        for (int b = 0; b < 4; ++b) {
            int lj = tx + 16 * b;
            int gj = tj * TILE + lj;
            if (gi < gj) {
                float s = acc[a][b];
                s = fminf(fmaxf(s, -CLIPV), CLIPV);
                float u = (s + CLIPV) * INVSTEP;
                int jb = (int)u;                 // u >= 0, trunc == floor
                if (jb > 98) jb = 98;
                float t_j = (float)jb * STEPF - 1.0f;
                float w_hi = (s - t_j) * INVSTEP;
                float w_lo = 1.0f - w_hi;
                float* h = (ca == clsB[lj]) ? hPos : hNeg;
                atomicAdd(&h[jb], w_lo);
                atomicAdd(&h[jb + 1], w_hi);
            }
        }
    }
    __syncthreads();
    if (tid < NSTEPS) {
        atomicAdd(&gPos[tid], hPos[tid]);
        atomicAdd(&gNeg[tid], hNeg[tid]);
    }
}

// ---------------- finalize: cumsum + dot ----------------
__global__ void hl_final(const float* __restrict__ hP, const float* __restrict__ hN,
                         float* __restrict__ out) {
    if (threadIdx.x == 0 && blockIdx.x == 0) {
        float sp = 0.f, sn = 0.f;
        for (int i = 0; i < NSTEPS; ++i) { sp += hP[i]; sn += hN[i]; }
        float invp = 1.0f / sp, invn = 1.0f / sn;
        float cdf = 0.f, loss = 0.f;
        for (int i = 0; i < NSTEPS; ++i) {
            cdf += hP[i] * invp;
            loss += hN[i] * invn * cdf;
        }
        out[0] = loss;
    }
}

extern "C" void kernel_launch(void* const* d_in, const int* in_sizes, int n_in,
                              void* d_out, int out_size, void* d_ws, size_t ws_size,
                              hipStream_t stream) {
    const float* emb = (const float*)d_in[0];
    const int* classes = (const int*)d_in[1];
    float* out = (float*)d_out;

    float* nemb = (float*)d_ws;                                   // 4096*128 fp32 = 2 MB
    float* hist = (float*)((char*)d_ws + (size_t)BN * DD * sizeof(float));
    float* hPos = hist;
    float* hNeg = hist + NSTEPS;

    hipMemsetAsync(hist, 0, 2 * NSTEPS * sizeof(float), stream);

    hl_normalize<<<BN / 4, 256, 0, stream>>>(emb, nemb);

    dim3 grid(BN / TILE, BN / TILE);  // 64 x 64; blocks with ti>tj early-exit
    hl_pair<<<grid, 256, 0, stream>>>(nemb, classes, hPos, hNeg);

    hl_final<<<1, 64, 0, stream>>>(hPos, hNeg, out);
}

// Round 2
// 186.889 us; speedup vs baseline: 9.1571x; 9.1571x over previous
//
#include <hip/hip_runtime.h>
#include <cstddef>

#define BN 4096
#define DD 128
#define NSTEPS 100
#define TILE 64
#define KSUB 64
#define LSTR 68   // KSUB + 4 pad: row stride 68 floats -> bank shift 4/row

// ---------------- normalize: one wave per row ----------------
__global__ __launch_bounds__(256) void hl_normalize(const float* __restrict__ emb,
                                                    float* __restrict__ out) {
    int w = threadIdx.x >> 6;
    int lane = threadIdx.x & 63;
    int row = (blockIdx.x << 2) + w;
    if (row >= BN) return;
    const float* r = emb + (size_t)row * DD;
    float x0 = r[lane];
    float x1 = r[lane + 64];
    float ss = x0 * x0 + x1 * x1;
    #pragma unroll
    for (int off = 32; off > 0; off >>= 1) ss += __shfl_xor(ss, off);
    float inv = 1.0f / sqrtf(ss);
    float* o = out + (size_t)row * DD;
    o[lane] = x0 * inv;
    o[lane + 64] = x1 * inv;
}

// ---------------- pair kernel: 64x64 tile pairs ----------------
__global__ __launch_bounds__(256, 2) void hl_pair(const float* __restrict__ nemb,
                                                  const int* __restrict__ cls,
                                                  float* __restrict__ gPos,
                                                  float* __restrict__ gNeg) {
    const int ti = blockIdx.y, tj = blockIdx.x;
    if (ti > tj) return;

    __shared__ float As[TILE][LSTR];
    __shared__ float Bs[TILE][LSTR];
    __shared__ int clsA[TILE], clsB[TILE];
    __shared__ float hPos[NSTEPS], hNeg[NSTEPS];

    const int tid = threadIdx.x;
    if (tid < NSTEPS) { hPos[tid] = 0.0f; hNeg[tid] = 0.0f; }
    if (tid >= 128 && tid < 128 + TILE) clsA[tid - 128] = cls[ti * TILE + (tid - 128)];
    if (tid >= 192)                     clsB[tid - 192] = cls[tj * TILE + (tid - 192)];

    const int tx = tid & 15;
    const int ty = tid >> 4;

    float acc[4][4] = {{0.f, 0.f, 0.f, 0.f}};

    #pragma unroll 1
    for (int kt = 0; kt < DD / KSUB; ++kt) {
        __syncthreads();  // also covers hist zero / cls load before first use
        // stage: 64 rows x 16 float4 per matrix, 256 threads -> 4 iters
        #pragma unroll 1
        for (int it = 0; it < 4; ++it) {
            int idx = it * 256 + tid;
            int row = idx >> 4;      // 0..63
            int kg = idx & 15;       // 0..15
            const float4 va = *(const float4*)(nemb + (size_t)(ti * TILE + row) * DD + kt * KSUB + kg * 4);
            const float4 vb = *(const float4*)(nemb + (size_t)(tj * TILE + row) * DD + kt * KSUB + kg * 4);
            *(float4*)(&As[row][kg * 4]) = va;
            *(float4*)(&Bs[row][kg * 4]) = vb;
        }
        __syncthreads();

        #pragma unroll 2
        for (int k = 0; k < KSUB; k += 4) {
            float4 a0 = *(const float4*)(&As[ty     ][k]);
            float4 a1 = *(const float4*)(&As[ty + 16][k]);
            float4 a2 = *(const float4*)(&As[ty + 32][k]);
            float4 a3 = *(const float4*)(&As[ty + 48][k]);
            float4 b0 = *(const float4*)(&Bs[tx     ][k]);
            float4 b1 = *(const float4*)(&Bs[tx + 16][k]);
            float4 b2 = *(const float4*)(&Bs[tx + 32][k]);
            float4 b3 = *(const float4*)(&Bs[tx + 48][k]);
            float4 av[4] = {a0, a1, a2, a3};
            float4 bv[4] = {b0, b1, b2, b3};
            #pragma unroll
            for (int a = 0; a < 4; ++a) {
                #pragma unroll
                for (int b = 0; b < 4; ++b) {
                    acc[a][b] += av[a].x * bv[b].x + av[a].y * bv[b].y
                               + av[a].z * bv[b].z + av[a].w * bv[b].w;
                }
            }
        }
    }

    // histogram accumulation into LDS
    constexpr float STEPF = 2.0f / 99.0f;
    constexpr float INVSTEP = 49.5f;          // exact
    constexpr float CLIPV = 1.0f - 1e-6f;

    #pragma unroll
    for (int a = 0; a < 4; ++a) {
        int li = ty + 16 * a;
        int gi = ti * TILE + li;
        int ca = clsA[li];
        #pragma unroll
        for (int b = 0; b < 4; ++b) {
            int lj = tx + 16 * b;
            int gj = tj * TILE + lj;
            if (gi < gj) {
                float s = acc[a][b];
                s = fminf(fmaxf(s, -CLIPV), CLIPV);
                float u = (s + CLIPV) * INVSTEP;
                int jb = (int)u;                 // u >= 0, trunc == floor
                if (jb > 98) jb = 98;
                float t_j = (float)jb * STEPF - 1.0f;
                float w_hi = (s - t_j) * INVSTEP;
                float w_lo = 1.0f - w_hi;
                float* h = (ca == clsB[lj]) ? hPos : hNeg;
                atomicAdd(&h[jb], w_lo);
                atomicAdd(&h[jb + 1], w_hi);
            }
        }
    }
    __syncthreads();
    if (tid < NSTEPS) {
        atomicAdd(&gPos[tid], hPos[tid]);
        atomicAdd(&gNeg[tid], hNeg[tid]);
    }
}

// ---------------- finalize: cumsum + dot ----------------
__global__ void hl_final(const float* __restrict__ hP, const float* __restrict__ hN,
                         float* __restrict__ out) {
    if (threadIdx.x == 0 && blockIdx.x == 0) {
        float sp = 0.f, sn = 0.f;
        for (int i = 0; i < NSTEPS; ++i) { sp += hP[i]; sn += hN[i]; }
        float invp = 1.0f / sp, invn = 1.0f / sn;
        float cdf = 0.f, loss = 0.f;
        for (int i = 0; i < NSTEPS; ++i) {
            cdf += hP[i] * invp;
            loss += hN[i] * invn * cdf;
        }
        out[0] = loss;
    }
}

extern "C" void kernel_launch(void* const* d_in, const int* in_sizes, int n_in,
                              void* d_out, int out_size, void* d_ws, size_t ws_size,
                              hipStream_t stream) {
    const float* emb = (const float*)d_in[0];
    const int* classes = (const int*)d_in[1];
    float* out = (float*)d_out;

    float* nemb = (float*)d_ws;                                   // 4096*128 fp32 = 2 MB
    float* hist = (float*)((char*)d_ws + (size_t)BN * DD * sizeof(float));
    float* hPos = hist;
    float* hNeg = hist + NSTEPS;

    hipMemsetAsync(hist, 0, 2 * NSTEPS * sizeof(float), stream);

    hl_normalize<<<BN / 4, 256, 0, stream>>>(emb, nemb);

    dim3 grid(BN / TILE, BN / TILE);  // 64 x 64; blocks with ti>tj early-exit
    hl_pair<<<grid, 256, 0, stream>>>(nemb, classes, hPos, hNeg);

    hl_final<<<1, 64, 0, stream>>>(hPos, hNeg, out);
}